// Round 1
// baseline (199.990 us; speedup 1.0000x reference)
//
#include <hip/hip_runtime.h>
#include <hip/hip_bf16.h>
#include <math.h>

#define S_LEN 2048
#define BATCH 4
#define HDIM 768
#define LOUT 9
#define NROWS (BATCH*S_LEN)
#define K2H 1536
#define WIN 11
#define NEG_INF_F (-1e30f)

typedef __attribute__((ext_vector_type(4))) float f32x4;
typedef __attribute__((ext_vector_type(8))) short bf16x8;

static __device__ __forceinline__ void async_ld16(const void* g, void* l) {
  __builtin_amdgcn_global_load_lds((const __attribute__((address_space(1))) void*)g,
                                   (__attribute__((address_space(3))) void*)l, 16, 0, 0);
}

static __device__ __forceinline__ unsigned short f2bf(float f) {
  union { float f; unsigned int u; } v; v.f = f;
  unsigned int u = v.u;
  unsigned int r = (u + 0x7fffu + ((u >> 16) & 1u)) >> 16;
  return (unsigned short)r;
}

// Kernel 1: x (fp32, [8192][768]) -> bf16 into first half of concat buffer xc [8192][1536]
__global__ __launch_bounds__(256) void k_prep_x(const float* __restrict__ x,
                                                unsigned short* __restrict__ xc) {
  int g = blockIdx.x * 256 + threadIdx.x;   // 4-element group; 1,572,864 groups total
  int row = g / 192;
  int c4 = (g % 192) * 4;
  const float4 v = *(const float4*)(x + row * HDIM + c4);
  ushort4 o;
  o.x = f2bf(v.x); o.y = f2bf(v.y); o.z = f2bf(v.z); o.w = f2bf(v.w);
  *(ushort4*)(xc + row * K2H + c4) = o;
}

// Kernel 2: W1 [1536][768] fp32 -> W1t [768][1536] bf16 (LDS-tiled transpose)
__global__ __launch_bounds__(256) void k_prep_w1t(const float* __restrict__ W1,
                                                  unsigned short* __restrict__ W1t) {
  __shared__ float tile[32][33];
  int bk = blockIdx.x % 48;   // k-tile (1536/32)
  int bn = blockIdx.x / 48;   // n-tile (768/32)
  int tc = threadIdx.x % 32;
  int tr = threadIdx.x / 32;  // 0..7
  #pragma unroll
  for (int i = 0; i < 32; i += 8) {
    tile[tr + i][tc] = W1[(bk*32 + tr + i) * HDIM + bn*32 + tc];
  }
  __syncthreads();
  #pragma unroll
  for (int i = 0; i < 32; i += 8) {
    W1t[(bn*32 + tr + i) * K2H + bk*32 + tc] = f2bf(tile[tc][tr + i]);
  }
}

// Kernel 3: scores[row] = x[row]·wa + ba   (one wave per row)
__global__ __launch_bounds__(256) void k_scores(const float* __restrict__ x,
                                                const float* __restrict__ wa,
                                                const float* __restrict__ ba,
                                                float* __restrict__ scores) {
  int wave = threadIdx.x >> 6, lane = threadIdx.x & 63;
  int row = blockIdx.x * 4 + wave;
  const float* xr = x + row * HDIM;
  float acc = 0.f;
  #pragma unroll
  for (int i = 0; i < 12; ++i) acc += xr[i*64 + lane] * wa[i*64 + lane];
  #pragma unroll
  for (int m = 1; m < 64; m <<= 1) acc += __shfl_xor(acc, m);
  if (lane == 0) scores[row] = acc + ba[0];
}

// Kernel 4: window softmax + weighted ctx (-> bf16 second half of xc) + base logits
__global__ __launch_bounds__(256) void k_ctx(const float* __restrict__ x,
                                             const float* __restrict__ scores,
                                             const float* __restrict__ Wc,
                                             const float* __restrict__ bc,
                                             unsigned short* __restrict__ xc,
                                             float* __restrict__ base) {
  __shared__ float scl[WIN];
  __shared__ float es[WIN];
  __shared__ int rowidx[WIN];
  __shared__ float red[4][LOUT];
  int row = blockIdx.x;
  int b = row >> 11, s = row & 2047;
  int t = threadIdx.x;
  if (t < WIN) {
    int j = s - 5 + t;
    bool valid = (j >= 0) && (j < S_LEN);
    int jc = valid ? j : (j < 0 ? 0 : S_LEN - 1);
    rowidx[t] = b * S_LEN + jc;
    scl[t] = valid ? scores[b * S_LEN + jc] : NEG_INF_F;
  }
  __syncthreads();
  float mx = scl[0];
  #pragma unroll
  for (int w = 1; w < WIN; ++w) mx = fmaxf(mx, scl[w]);
  if (t < WIN) {
    float sv = scl[t];
    es[t] = (sv > -1e29f) ? __expf(sv - mx) : 0.f;
  }
  __syncthreads();
  float ssum = 0.f;
  #pragma unroll
  for (int w = 0; w < WIN; ++w) ssum += es[w];
  float inv = 1.f / ssum;
  float acc0 = 0.f, acc1 = 0.f, acc2 = 0.f;
  #pragma unroll
  for (int w = 0; w < WIN; ++w) {
    float aw = es[w] * inv;
    const float* xr = x + rowidx[w] * HDIM;
    acc0 += aw * xr[t];
    acc1 += aw * xr[t + 256];
    acc2 += aw * xr[t + 512];
  }
  unsigned short* dst = xc + row * K2H + HDIM;
  dst[t]       = f2bf(acc0);
  dst[t + 256] = f2bf(acc1);
  dst[t + 512] = f2bf(acc2);
  // base logits: x[row]·Wc (9 cols)
  const float* xr = x + row * HDIM;
  float p[LOUT] = {};
  #pragma unroll
  for (int i = 0; i < 3; ++i) {
    int e = t + i * 256;
    float xv = xr[e];
    const float* wrow = Wc + e * LOUT;
    #pragma unroll
    for (int l = 0; l < LOUT; ++l) p[l] += xv * wrow[l];
  }
  #pragma unroll
  for (int l = 0; l < LOUT; ++l) {
    #pragma unroll
    for (int m = 1; m < 64; m <<= 1) p[l] += __shfl_xor(p[l], m);
  }
  int lane = t & 63, wave = t >> 6;
  if (lane == 0) {
    #pragma unroll
    for (int l = 0; l < LOUT; ++l) red[wave][l] = p[l];
  }
  __syncthreads();
  if (t < LOUT) {
    base[row * LOUT + t] = red[0][t] + red[1][t] + red[2][t] + red[3][t] + bc[t];
  }
}

// Kernel 5: h = xc(bf16,[8192][1536]) @ W1t^T + b1 -> fp32 [8192][768]
// m97-style: 128x128 tile, BK=32, 4 waves each 64x64, global_load_lds width 16.
__global__ __launch_bounds__(256) void k_gemm(const unsigned short* __restrict__ A,
                                              const unsigned short* __restrict__ Bt,
                                              const float* __restrict__ b1,
                                              float* __restrict__ Hout) {
  __shared__ unsigned short As[128 * 32];
  __shared__ unsigned short Bs[128 * 32];
  int bid = blockIdx.x;
  int bm = bid / 6, bn = bid % 6;   // M tiles 64, N tiles 6
  int t = threadIdx.x;
  int lane = t & 63, wave = t >> 6;
  int wm = wave >> 1, wn = wave & 1;
  int e0 = t * 8;
  int r0 = e0 >> 5, c0 = e0 & 31;
  const unsigned short* gA0 = A + (bm * 128 + r0) * K2H + c0;
  const unsigned short* gB0 = Bt + (bn * 128 + r0) * K2H + c0;
  unsigned short* lA = As + wave * 512;   // wave-uniform dest; HW adds lane*16B
  unsigned short* lB = Bs + wave * 512;
  f32x4 acc[4][4] = {};
  int laneRow = lane & 15;
  int laneK = (lane >> 4) * 8;
  const unsigned short* aBase = As + (wm * 64 + laneRow) * 32 + laneK;
  const unsigned short* bBase = Bs + (wn * 64 + laneRow) * 32 + laneK;

  for (int kt = 0; kt < K2H; kt += 32) {
    __syncthreads();
    async_ld16(gA0 + kt, lA);
    async_ld16(gA0 + 64 * K2H + kt, lA + 2048);
    async_ld16(gB0 + kt, lB);
    async_ld16(gB0 + 64 * K2H + kt, lB + 2048);
    __syncthreads();
    bf16x8 a[4], bfr[4];
    #pragma unroll
    for (int m = 0; m < 4; ++m) a[m] = *(const bf16x8*)(aBase + m * 16 * 32);
    #pragma unroll
    for (int n = 0; n < 4; ++n) bfr[n] = *(const bf16x8*)(bBase + n * 16 * 32);
    #pragma unroll
    for (int m = 0; m < 4; ++m)
      #pragma unroll
      for (int n = 0; n < 4; ++n)
        acc[m][n] = __builtin_amdgcn_mfma_f32_16x16x32_bf16(a[m], bfr[n], acc[m][n], 0, 0, 0);
  }
  int orow = bm * 128 + wm * 64 + (lane >> 4) * 4;
  int ocol = bn * 128 + wn * 64 + (lane & 15);
  #pragma unroll
  for (int m = 0; m < 4; ++m)
    #pragma unroll
    for (int n = 0; n < 4; ++n) {
      int col = ocol + n * 16;
      float bv = b1[col];
      #pragma unroll
      for (int r = 0; r < 4; ++r) {
        Hout[(orow + m * 16 + r) * HDIM + col] = acc[m][n][r] + bv;
      }
    }
}

// Kernel 6: LayerNorm + exact GELU + W2 matvec (9) + 0.5/0.5 combine with base
__global__ __launch_bounds__(256) void k_ln(const float* __restrict__ Hin,
                                            const float* __restrict__ gamma,
                                            const float* __restrict__ beta,
                                            const float* __restrict__ W2,
                                            const float* __restrict__ b2,
                                            const float* __restrict__ base,
                                            float* __restrict__ out) {
  __shared__ float redS[4], redQ[4], redp[4][LOUT];
  int row = blockIdx.x;
  int t = threadIdx.x;
  int lane = t & 63, wave = t >> 6;
  const float* hr = Hin + row * HDIM;
  float v0 = hr[t], v1 = hr[t + 256], v2 = hr[t + 512];
  float s1 = v0 + v1 + v2;
  float s2 = v0 * v0 + v1 * v1 + v2 * v2;
  #pragma unroll
  for (int m = 1; m < 64; m <<= 1) { s1 += __shfl_xor(s1, m); s2 += __shfl_xor(s2, m); }
  if (lane == 0) { redS[wave] = s1; redQ[wave] = s2; }
  __syncthreads();
  s1 = redS[0] + redS[1] + redS[2] + redS[3];
  s2 = redQ[0] + redQ[1] + redQ[2] + redQ[3];
  float mu = s1 * (1.f / HDIM);
  float var = s2 * (1.f / HDIM) - mu * mu;
  float rstd = rsqrtf(var + 1e-5f);
  float p[LOUT] = {};
  float vv[3] = { v0, v1, v2 };
  #pragma unroll
  for (int i = 0; i < 3; ++i) {
    int e = t + i * 256;
    float g = (vv[i] - mu) * rstd * gamma[e] + beta[e];
    float gg = 0.5f * g * (1.f + erff(g * 0.70710678118654752f));
    const float* wrow = W2 + e * LOUT;
    #pragma unroll
    for (int l = 0; l < LOUT; ++l) p[l] += gg * wrow[l];
  }
  #pragma unroll
  for (int l = 0; l < LOUT; ++l) {
    #pragma unroll
    for (int m = 1; m < 64; m <<= 1) p[l] += __shfl_xor(p[l], m);
  }
  if (lane == 0) {
    #pragma unroll
    for (int l = 0; l < LOUT; ++l) redp[wave][l] = p[l];
  }
  __syncthreads();
  if (t < LOUT) {
    float cl = redp[0][t] + redp[1][t] + redp[2][t] + redp[3][t] + b2[t];
    out[row * LOUT + t] = 0.5f * base[row * LOUT + t] + 0.5f * cl;
  }
}

extern "C" void kernel_launch(void* const* d_in, const int* in_sizes, int n_in,
                              void* d_out, int out_size, void* d_ws, size_t ws_size,
                              hipStream_t stream) {
  const float* x     = (const float*)d_in[0];
  const float* Wc    = (const float*)d_in[1];
  const float* bc    = (const float*)d_in[2];
  const float* wa    = (const float*)d_in[3];
  const float* ba    = (const float*)d_in[4];
  const float* W1    = (const float*)d_in[5];
  const float* b1    = (const float*)d_in[6];
  const float* gamma = (const float*)d_in[7];
  const float* beta  = (const float*)d_in[8];
  const float* W2    = (const float*)d_in[9];
  const float* b2    = (const float*)d_in[10];
  float* out = (float*)d_out;

  char* ws = (char*)d_ws;
  unsigned short* xc  = (unsigned short*)(ws);             // 8192*1536*2  = 25,165,824
  unsigned short* w1t = (unsigned short*)(ws + 25165824);  // 768*1536*2   =  2,359,296
  float* scores       = (float*)(ws + 27525120);           // 8192*4       =     32,768
  float* base         = (float*)(ws + 27557888);           // 8192*9*4     =    294,912
  float* hbuf         = (float*)(ws + 27852800);           // 8192*768*4   = 25,165,824
                                                           // total 53,018,624 bytes

  k_prep_x  <<<dim3(6144), dim3(256), 0, stream>>>(x, xc);
  k_prep_w1t<<<dim3(1152), dim3(256), 0, stream>>>(W1, w1t);
  k_scores  <<<dim3(2048), dim3(256), 0, stream>>>(x, wa, ba, scores);
  k_ctx     <<<dim3(8192), dim3(256), 0, stream>>>(x, scores, Wc, bc, xc, base);
  k_gemm    <<<dim3(384),  dim3(256), 0, stream>>>(xc, w1t, b1, hbuf);
  k_ln      <<<dim3(8192), dim3(256), 0, stream>>>(hbuf, gamma, beta, W2, b2, base, out);
}

// Round 3
// 194.544 us; speedup vs baseline: 1.0280x; 1.0280x over previous
//
#include <hip/hip_runtime.h>
#include <hip/hip_bf16.h>
#include <math.h>

#define S_LEN 2048
#define BATCH 4
#define HDIM 768
#define LOUT 9
#define NROWS (BATCH*S_LEN)
#define K2H 1536
#define WIN 11
#define NEG_INF_F (-1e30f)

typedef __attribute__((ext_vector_type(4))) float f32x4;
typedef __attribute__((ext_vector_type(8))) short bf16x8;

static __device__ __forceinline__ void async_ld16(const void* g, void* l) {
  __builtin_amdgcn_global_load_lds((const __attribute__((address_space(1))) void*)g,
                                   (__attribute__((address_space(3))) void*)l, 16, 0, 0);
}

static __device__ __forceinline__ unsigned short f2bf(float f) {
  union { float f; unsigned int u; } v; v.f = f;
  unsigned int u = v.u;
  unsigned int r = (u + 0x7fffu + ((u >> 16) & 1u)) >> 16;
  return (unsigned short)r;
}

// Kernel 1 (fused): x (fp32 [8192][768]) -> bf16 first half of xc [8192][1536]
//                   + scores[row] = x[row]·wa + ba
// One block per row, 192 threads (3 waves), each thread one float4.
__global__ __launch_bounds__(192) void k_prep(const float* __restrict__ x,
                                              const float* __restrict__ wa,
                                              const float* __restrict__ ba,
                                              unsigned short* __restrict__ xc,
                                              float* __restrict__ scores) {
  __shared__ float red[3];
  int row = blockIdx.x;
  int t = threadIdx.x;
  int lane = t & 63, wave = t >> 6;
  const float4 v = *(const float4*)(x + row * HDIM + t * 4);
  const float4 w = *(const float4*)(wa + t * 4);
  ushort4 o;
  o.x = f2bf(v.x); o.y = f2bf(v.y); o.z = f2bf(v.z); o.w = f2bf(v.w);
  *(ushort4*)(xc + row * K2H + t * 4) = o;
  float p = v.x * w.x + v.y * w.y + v.z * w.z + v.w * w.w;
  #pragma unroll
  for (int m = 1; m < 64; m <<= 1) p += __shfl_xor(p, m);
  if (lane == 0) red[wave] = p;
  __syncthreads();
  if (t == 0) scores[row] = red[0] + red[1] + red[2] + ba[0];
}

// Kernel 2: W1 [1536][768] fp32 -> W1t [768][1536] bf16 (LDS-tiled transpose)
__global__ __launch_bounds__(256) void k_prep_w1t(const float* __restrict__ W1,
                                                  unsigned short* __restrict__ W1t) {
  __shared__ float tile[32][33];
  int bk = blockIdx.x % 48;   // k-tile (1536/32)
  int bn = blockIdx.x / 48;   // n-tile (768/32)
  int tc = threadIdx.x % 32;
  int tr = threadIdx.x / 32;  // 0..7
  #pragma unroll
  for (int i = 0; i < 32; i += 8) {
    tile[tr + i][tc] = W1[(bk*32 + tr + i) * HDIM + bn*32 + tc];
  }
  __syncthreads();
  #pragma unroll
  for (int i = 0; i < 32; i += 8) {
    W1t[(bn*32 + tr + i) * K2H + bk*32 + tc] = f2bf(tile[tc][tr + i]);
  }
}

// Kernel 3: window softmax + weighted ctx (-> bf16 second half of xc) + base logits
__global__ __launch_bounds__(256) void k_ctx(const float* __restrict__ x,
                                             const float* __restrict__ scores,
                                             const float* __restrict__ Wc,
                                             const float* __restrict__ bc,
                                             unsigned short* __restrict__ xc,
                                             float* __restrict__ base) {
  __shared__ float scl[WIN];
  __shared__ float es[WIN];
  __shared__ int rowidx[WIN];
  __shared__ float red[4][LOUT];
  int row = blockIdx.x;
  int b = row >> 11, s = row & 2047;
  int t = threadIdx.x;
  if (t < WIN) {
    int j = s - 5 + t;
    bool valid = (j >= 0) && (j < S_LEN);
    int jc = valid ? j : (j < 0 ? 0 : S_LEN - 1);
    rowidx[t] = b * S_LEN + jc;
    scl[t] = valid ? scores[b * S_LEN + jc] : NEG_INF_F;
  }
  __syncthreads();
  float mx = scl[0];
  #pragma unroll
  for (int w = 1; w < WIN; ++w) mx = fmaxf(mx, scl[w]);
  if (t < WIN) {
    float sv = scl[t];
    es[t] = (sv > -1e29f) ? __expf(sv - mx) : 0.f;
  }
  __syncthreads();
  float ssum = 0.f;
  #pragma unroll
  for (int w = 0; w < WIN; ++w) ssum += es[w];
  float inv = 1.f / ssum;
  float acc0 = 0.f, acc1 = 0.f, acc2 = 0.f;
  #pragma unroll
  for (int w = 0; w < WIN; ++w) {
    float aw = es[w] * inv;
    const float* xr = x + rowidx[w] * HDIM;
    acc0 += aw * xr[t];
    acc1 += aw * xr[t + 256];
    acc2 += aw * xr[t + 512];
  }
  unsigned short* dst = xc + row * K2H + HDIM;
  dst[t]       = f2bf(acc0);
  dst[t + 256] = f2bf(acc1);
  dst[t + 512] = f2bf(acc2);
  // base logits: x[row]·Wc (9 cols)
  const float* xr = x + row * HDIM;
  float p[LOUT] = {};
  #pragma unroll
  for (int i = 0; i < 3; ++i) {
    int e = t + i * 256;
    float xv = xr[e];
    const float* wrow = Wc + e * LOUT;
    #pragma unroll
    for (int l = 0; l < LOUT; ++l) p[l] += xv * wrow[l];
  }
  #pragma unroll
  for (int l = 0; l < LOUT; ++l) {
    #pragma unroll
    for (int m = 1; m < 64; m <<= 1) p[l] += __shfl_xor(p[l], m);
  }
  int lane = t & 63, wave = t >> 6;
  if (lane == 0) {
    #pragma unroll
    for (int l = 0; l < LOUT; ++l) red[wave][l] = p[l];
  }
  __syncthreads();
  if (t < LOUT) {
    base[row * LOUT + t] = red[0][t] + red[1][t] + red[2][t] + red[3][t] + bc[t];
  }
}

// Kernel 4: h = xc(bf16,[8192][1536]) @ W1t^T + b1 -> fp32 [8192][768]
// 128x64 tile, BK=64, 4 waves (each 32x64), double-buffered LDS with
// prefetch: STAGE(next) issued before COMPUTE(cur); one barrier per K-step.
// Grid 64*12 = 768 blocks (3/CU). XCD-bijective swizzle (768%8==0).
__global__ __launch_bounds__(256) void k_gemm(const unsigned short* __restrict__ A,
                                              const unsigned short* __restrict__ Bt,
                                              const float* __restrict__ b1,
                                              float* __restrict__ Hout) {
  __shared__ unsigned short As[2][128 * 64];  // 32 KB
  __shared__ unsigned short Bs[2][64 * 64];   // 16 KB
  int bid = blockIdx.x;
  int obid = (bid & 7) * 96 + (bid >> 3);     // XCD swizzle: 8 A-panels per XCD
  int bm = obid / 12, bn = obid % 12;
  int t = threadIdx.x;
  int lane = t & 63, wave = t >> 6;
  int rsub = lane >> 3;    // row within 8-row chunk
  int kslot = lane & 7;    // 16B slot within 128B row

  // per-thread global element offsets (row part), k added per iter
  int aRow0 = bm * 128 + (wave * 4 + 0) * 8 + rsub;
  int bRow0 = bn * 64  + (wave * 2 + 0) * 8 + rsub;
  const unsigned short* gA = A  + aRow0 * K2H + kslot * 8;
  const unsigned short* gB = Bt + bRow0 * K2H + kslot * 8;

  f32x4 acc[2][4] = {};
  int laneRow = lane & 15;
  int laneK = (lane >> 4) * 8;
  const unsigned short* aBase0 = &As[0][(wave * 32 + laneRow) * 64 + laneK];
  const unsigned short* bBase0 = &Bs[0][laneRow * 64 + laneK];

#define STAGE(buf, kt) do {                                                   \
    _Pragma("unroll")                                                         \
    for (int j = 0; j < 4; ++j)                                               \
      async_ld16(gA + j * 8 * K2H + (kt), &As[buf][(wave * 4 + j) * 512]);    \
    _Pragma("unroll")                                                         \
    for (int j = 0; j < 2; ++j)                                               \
      async_ld16(gB + j * 8 * K2H + (kt), &Bs[buf][(wave * 2 + j) * 512]);    \
  } while (0)

#define COMPUTE(buf) do {                                                     \
    const unsigned short* aB = aBase0 + (buf) * 128 * 64;                     \
    const unsigned short* bB = bBase0 + (buf) * 64 * 64;                      \
    _Pragma("unroll")                                                         \
    for (int kk = 0; kk < 2; ++kk) {                                          \
      bf16x8 af[2], bf[4];                                                    \
      _Pragma("unroll")                                                       \
      for (int m = 0; m < 2; ++m) af[m] = *(const bf16x8*)(aB + m*16*64 + kk*32); \
      _Pragma("unroll")                                                       \
      for (int n = 0; n < 4; ++n) bf[n] = *(const bf16x8*)(bB + n*16*64 + kk*32); \
      _Pragma("unroll")                                                       \
      for (int m = 0; m < 2; ++m)                                             \
        _Pragma("unroll")                                                     \
        for (int n = 0; n < 4; ++n)                                           \
          acc[m][n] = __builtin_amdgcn_mfma_f32_16x16x32_bf16(af[m], bf[n], acc[m][n], 0, 0, 0); \
    }                                                                         \
  } while (0)

  STAGE(0, 0);
  __syncthreads();               // drains vmcnt(0) before barrier
  int cur = 0;
  for (int kt = 64; kt < K2H; kt += 64) {
    STAGE(cur ^ 1, kt);          // prefetch next tile (stays in flight during MFMA)
    COMPUTE(cur);
    __syncthreads();
    cur ^= 1;
  }
  COMPUTE(cur);

  int orow = bm * 128 + wave * 32 + (lane >> 4) * 4;
  int ocol = bn * 64 + (lane & 15);
  #pragma unroll
  for (int m = 0; m < 2; ++m)
    #pragma unroll
    for (int n = 0; n < 4; ++n) {
      int col = ocol + n * 16;
      float bv = b1[col];
      #pragma unroll
      for (int r = 0; r < 4; ++r) {
        Hout[(orow + m * 16 + r) * HDIM + col] = acc[m][n][r] + bv;
      }
    }
#undef STAGE
#undef COMPUTE
}

// Kernel 5: LayerNorm + exact GELU + W2 matvec (9) + 0.5/0.5 combine with base
__global__ __launch_bounds__(256) void k_ln(const float* __restrict__ Hin,
                                            const float* __restrict__ gamma,
                                            const float* __restrict__ beta,
                                            const float* __restrict__ W2,
                                            const float* __restrict__ b2,
                                            const float* __restrict__ base,
                                            float* __restrict__ out) {
  __shared__ float redS[4], redQ[4], redp[4][LOUT];
  int row = blockIdx.x;
  int t = threadIdx.x;
  int lane = t & 63, wave = t >> 6;
  const float* hr = Hin + row * HDIM;
  float v0 = hr[t], v1 = hr[t + 256], v2 = hr[t + 512];
  float s1 = v0 + v1 + v2;
  float s2 = v0 * v0 + v1 * v1 + v2 * v2;
  #pragma unroll
  for (int m = 1; m < 64; m <<= 1) { s1 += __shfl_xor(s1, m); s2 += __shfl_xor(s2, m); }
  if (lane == 0) { redS[wave] = s1; redQ[wave] = s2; }
  __syncthreads();
  s1 = redS[0] + redS[1] + redS[2] + redS[3];
  s2 = redQ[0] + redQ[1] + redQ[2] + redQ[3];
  float mu = s1 * (1.f / HDIM);
  float var = s2 * (1.f / HDIM) - mu * mu;
  float rstd = rsqrtf(var + 1e-5f);
  float p[LOUT] = {};
  float vv[3] = { v0, v1, v2 };
  #pragma unroll
  for (int i = 0; i < 3; ++i) {
    int e = t + i * 256;
    float g = (vv[i] - mu) * rstd * gamma[e] + beta[e];
    float gg = 0.5f * g * (1.f + erff(g * 0.70710678118654752f));
    const float* wrow = W2 + e * LOUT;
    #pragma unroll
    for (int l = 0; l < LOUT; ++l) p[l] += gg * wrow[l];
  }
  #pragma unroll
  for (int l = 0; l < LOUT; ++l) {
    #pragma unroll
    for (int m = 1; m < 64; m <<= 1) p[l] += __shfl_xor(p[l], m);
  }
  if (lane == 0) {
    #pragma unroll
    for (int l = 0; l < LOUT; ++l) redp[wave][l] = p[l];
  }
  __syncthreads();
  if (t < LOUT) {
    float cl = redp[0][t] + redp[1][t] + redp[2][t] + redp[3][t] + b2[t];
    out[row * LOUT + t] = 0.5f * base[row * LOUT + t] + 0.5f * cl;
  }
}

extern "C" void kernel_launch(void* const* d_in, const int* in_sizes, int n_in,
                              void* d_out, int out_size, void* d_ws, size_t ws_size,
                              hipStream_t stream) {
  const float* x     = (const float*)d_in[0];
  const float* Wc    = (const float*)d_in[1];
  const float* bc    = (const float*)d_in[2];
  const float* wa    = (const float*)d_in[3];
  const float* ba    = (const float*)d_in[4];
  const float* W1    = (const float*)d_in[5];
  const float* b1    = (const float*)d_in[6];
  const float* gamma = (const float*)d_in[7];
  const float* beta  = (const float*)d_in[8];
  const float* W2    = (const float*)d_in[9];
  const float* b2    = (const float*)d_in[10];
  float* out = (float*)d_out;

  char* ws = (char*)d_ws;
  unsigned short* xc  = (unsigned short*)(ws);             // 8192*1536*2  = 25,165,824
  unsigned short* w1t = (unsigned short*)(ws + 25165824);  // 768*1536*2   =  2,359,296
  float* scores       = (float*)(ws + 27525120);           // 8192*4       =     32,768
  float* base         = (float*)(ws + 27557888);           // 8192*9*4     =    294,912
  float* hbuf         = (float*)(ws + 27852800);           // 8192*768*4   = 25,165,824

  k_prep    <<<dim3(8192), dim3(192), 0, stream>>>(x, wa, ba, xc, scores);
  k_prep_w1t<<<dim3(1152), dim3(256), 0, stream>>>(W1, w1t);
  k_ctx     <<<dim3(8192), dim3(256), 0, stream>>>(x, scores, Wc, bc, xc, base);
  k_gemm    <<<dim3(768),  dim3(256), 0, stream>>>(xc, w1t, b1, hbuf);
  k_ln      <<<dim3(8192), dim3(256), 0, stream>>>(hbuf, gamma, beta, W2, b2, base, out);
}